// Round 1
// baseline (97.491 us; speedup 1.0000x reference)
//
#include <hip/hip_runtime.h>

#define IN_F 8192
#define OUT_F 8192
#define BATCH 64
#define PASS 2048      // mu-scan pass size; LDS list sized to PASS => no overflow ever
#define TQ 64          // output columns per tile
#define CH 64          // list chunk size for x staging

// ---------------- Kernel 1: transpose x [64, 8192] -> xT [8192, 64] ----------------
__global__ __launch_bounds__(256) void transpose_x_kern(const float* __restrict__ x,
                                                        float* __restrict__ xT) {
    __shared__ float tile[64][65];   // +1 pad: conflict-free
    const int i0 = blockIdx.x * 64;
    const int tid = threadIdx.x;
#pragma unroll
    for (int u = tid; u < 64 * 64; u += 256) {
        const int b = u >> 6;          // batch row
        const int i = u & 63;          // feature within tile (fastest -> coalesced)
        tile[i][b] = x[b * IN_F + i0 + i];
    }
    __syncthreads();
#pragma unroll
    for (int u = tid; u < 64 * 64; u += 256) {
        const int i = u >> 6;
        const int b = u & 63;          // fastest -> coalesced writes
        xT[(i0 + i) * 64 + b] = tile[i][b];
    }
}

// ---------------- Kernel 2: banded Gaussian FC ----------------
// grid.x = OUT_F/TQ = 128 tiles, grid.y = 4 batch quarters (16 rows each)
// block = 256: c = tid&63 (column in tile), g = tid>>6 (row subgroup, 4 rows each)
__global__ __launch_bounds__(256) void gauss_fc_kern(
    const float* __restrict__ x, const float* __restrict__ xT,
    const float* __restrict__ mu, const float* __restrict__ sigma,
    const float* __restrict__ amp, const float* __restrict__ bias,
    float* __restrict__ out, const int use_xt) {

    __shared__ float lmu[PASS];
    __shared__ float lk[PASS];
    __shared__ float lamp[PASS];
    __shared__ int   li[PASS];
    __shared__ float xs[CH][16];
    __shared__ int   cnt;

    const int tid = threadIdx.x;
    const int c = tid & 63;
    const int g = tid >> 6;                    // 0..3
    const int tile0 = blockIdx.x * TQ;
    const int row0 = blockIdx.y * 16;          // batch quarter base row
    const float colf = (float)(tile0 + c);
    const float lo = (float)tile0;
    const float hi = (float)(tile0 + TQ - 1);

    float acc0 = 0.f, acc1 = 0.f, acc2 = 0.f, acc3 = 0.f;

    for (int base = 0; base < IN_F; base += PASS) {
        if (tid == 0) cnt = 0;
        __syncthreads();

        // ---- build qualifying-feature list for this pass ----
        for (int i = base + tid; i < base + PASS; i += 256) {
            const float m = mu[i];
            const float s = sigma[i];
            const float R = 8.0f * fabsf(s) + 1.0f;   // exp(-32) ~ 1e-14: negligible beyond
            if (m >= lo - R && m <= hi + R) {
                const int p = atomicAdd(&cnt, 1);      // p < PASS guaranteed
                lmu[p] = m;
                lk[p] = -0.5f / (s * s);
                lamp[p] = amp[i];
                li[p] = i;
            }
        }
        __syncthreads();
        const int n = cnt;

        // ---- process list in chunks: stage x columns, then accumulate ----
        for (int cb = 0; cb < n; cb += CH) {
            const int cn = min(CH, n - cb);
            for (int u = tid; u < (cn << 4); u += 256) {
                const int ci = u >> 4;
                const int r = u & 15;                  // row within quarter (fastest)
                const int i = li[cb + ci];
                xs[ci][r] = use_xt ? xT[i * 64 + row0 + r]
                                   : x[(row0 + r) * IN_F + i];
            }
            __syncthreads();

            const int g4 = g << 2;
#pragma unroll 4
            for (int j = 0; j < cn; ++j) {
                const float m = lmu[cb + j];
                const float k = lk[cb + j];
                const float a = lamp[cb + j];
                const float d = colf - m;
                const float w = a * __expf(k * d * d);
                acc0 += w * xs[j][g4 + 0];
                acc1 += w * xs[j][g4 + 1];
                acc2 += w * xs[j][g4 + 2];
                acc3 += w * xs[j][g4 + 3];
            }
            __syncthreads();
        }
    }

    // ---- epilogue: + bias, ReLU, coalesced stores ----
    const float bb = bias[tile0 + c];
    float* o = out + (size_t)(row0 + (g << 2)) * OUT_F + tile0 + c;
    float v0 = acc0 + bb;
    float v1 = acc1 + bb;
    float v2 = acc2 + bb;
    float v3 = acc3 + bb;
    o[0 * (size_t)OUT_F] = v0 > 0.f ? v0 : 0.f;
    o[1 * (size_t)OUT_F] = v1 > 0.f ? v1 : 0.f;
    o[2 * (size_t)OUT_F] = v2 > 0.f ? v2 : 0.f;
    o[3 * (size_t)OUT_F] = v3 > 0.f ? v3 : 0.f;
}

extern "C" void kernel_launch(void* const* d_in, const int* in_sizes, int n_in,
                              void* d_out, int out_size, void* d_ws, size_t ws_size,
                              hipStream_t stream) {
    const float* x     = (const float*)d_in[0];   // [64, 8192]
    const float* mu    = (const float*)d_in[1];   // [8192]
    const float* sigma = (const float*)d_in[2];   // [8192]
    const float* amp   = (const float*)d_in[3];   // [8192]
    const float* bias  = (const float*)d_in[4];   // [8192]
    float* out = (float*)d_out;

    const size_t xt_bytes = (size_t)IN_F * BATCH * sizeof(float);
    const int use_xt = (ws_size >= xt_bytes) ? 1 : 0;
    float* xT = (float*)d_ws;

    if (use_xt) {
        transpose_x_kern<<<IN_F / 64, 256, 0, stream>>>(x, xT);
    }
    dim3 grid(OUT_F / TQ, 4);
    gauss_fc_kern<<<grid, 256, 0, stream>>>(x, xT, mu, sigma, amp, bias, out, use_xt);
}

// Round 2
// 95.903 us; speedup vs baseline: 1.0166x; 1.0166x over previous
//
#include <hip/hip_runtime.h>

#define IN_F 8192
#define OUT_F 8192
#define BATCH 64
#define PASS 2048      // mu-scan pass size; list cap == PASS => overflow impossible
#define TQ 32          // output columns per tile
#define ROWS 16        // batch rows per block
#define CH 64          // list chunk size for x staging

// ---------------- Kernel 1: transpose x [64, 8192] -> xT [8192, 64] ----------------
__global__ __launch_bounds__(256) void transpose_x_kern(const float* __restrict__ x,
                                                        float* __restrict__ xT) {
    __shared__ float tile[64][65];   // +1 pad: conflict-free
    const int i0 = blockIdx.x * 64;
    const int tid = threadIdx.x;
#pragma unroll
    for (int u = tid; u < 64 * 64; u += 256) {
        const int b = u >> 6;
        const int i = u & 63;          // fastest -> coalesced reads
        tile[i][b] = x[b * IN_F + i0 + i];
    }
    __syncthreads();
#pragma unroll
    for (int u = tid; u < 64 * 64; u += 256) {
        const int i = u >> 6;
        const int b = u & 63;          // fastest -> coalesced writes
        xT[(i0 + i) * 64 + b] = tile[i][b];
    }
}

// ---------------- Kernel 2: banded Gaussian FC ----------------
// grid = (OUT_F/TQ = 256, BATCH/ROWS = 4) = 1024 blocks -> 4 blocks/CU, 16 waves/CU.
// block 256: c = tid&31 (column in tile), g = tid>>5 (0..7), 2 rows per thread.
__global__ __launch_bounds__(256, 4) void gauss_fc_kern(
    const float* __restrict__ x, const float* __restrict__ xT,
    const float4* __restrict__ mu4, const float4* __restrict__ sg4,
    const float* __restrict__ amp, const float* __restrict__ bias,
    float* __restrict__ out, const int use_xt) {

    __shared__ float lmu[PASS];
    __shared__ float lk[PASS];
    __shared__ float lamp[PASS];
    __shared__ int   li[PASS];
    __shared__ float xs[CH][ROWS];
    __shared__ int   cnt;

    const int tid = threadIdx.x;
    const int c = tid & 31;
    const int g = tid >> 5;                    // 0..7
    const int tile0 = blockIdx.x * TQ;
    const int row0 = blockIdx.y * ROWS;
    const float colf = (float)(tile0 + c);
    const float lo = (float)tile0;
    const float hi = (float)(tile0 + TQ - 1);

    float acc0 = 0.f, acc1 = 0.f;

    for (int base = 0; base < IN_F; base += PASS) {
        if (tid == 0) cnt = 0;
        __syncthreads();

        // ---- float4 scan + compaction: PASS/4 = 512 float4 over 256 threads ----
        const int q_end = (base + PASS) >> 2;
        for (int q = (base >> 2) + tid; q < q_end; q += 256) {
            const float4 m4 = mu4[q];
            const float4 s4 = sg4[q];
            const float ms[4] = {m4.x, m4.y, m4.z, m4.w};
            const float ss[4] = {s4.x, s4.y, s4.z, s4.w};
#pragma unroll
            for (int e = 0; e < 4; ++e) {
                const float m = ms[e];
                const float s = ss[e];
                const float R = 8.0f * fabsf(s) + 1.0f;   // dropped terms < exp(-32)
                if (m >= lo - R && m <= hi + R) {
                    const int i = (q << 2) + e;
                    const int p = atomicAdd(&cnt, 1);     // p < PASS guaranteed
                    lmu[p] = m;
                    lk[p] = -0.5f / (s * s);
                    lamp[p] = amp[i];
                    li[p] = i;
                }
            }
        }
        __syncthreads();
        const int n = cnt;

        // ---- chunks: stage x columns (1 cache line per entry via xT), accumulate ----
        for (int cb = 0; cb < n; cb += CH) {
            const int cn = min(CH, n - cb);
            for (int u = tid; u < (cn << 4); u += 256) {
                const int ci = u >> 4;
                const int r = u & 15;
                const int i = li[cb + ci];
                xs[ci][r] = use_xt ? xT[i * 64 + row0 + r]
                                   : x[(size_t)(row0 + r) * IN_F + i];
            }
            __syncthreads();

            const int g2 = g << 1;
#pragma unroll 4
            for (int j = 0; j < cn; ++j) {
                const float d = colf - lmu[cb + j];
                const float w = lamp[cb + j] * __expf(lk[cb + j] * d * d);
                acc0 += w * xs[j][g2 + 0];
                acc1 += w * xs[j][g2 + 1];
            }
            __syncthreads();
        }
    }

    // ---- epilogue: + bias, ReLU, coalesced stores ----
    const float bb = bias[tile0 + c];
    const int r0 = row0 + (g << 1);
    const float v0 = acc0 + bb;
    const float v1 = acc1 + bb;
    out[(size_t)r0 * OUT_F + tile0 + c]       = v0 > 0.f ? v0 : 0.f;
    out[(size_t)(r0 + 1) * OUT_F + tile0 + c] = v1 > 0.f ? v1 : 0.f;
}

extern "C" void kernel_launch(void* const* d_in, const int* in_sizes, int n_in,
                              void* d_out, int out_size, void* d_ws, size_t ws_size,
                              hipStream_t stream) {
    const float* x     = (const float*)d_in[0];   // [64, 8192]
    const float* mu    = (const float*)d_in[1];   // [8192]
    const float* sigma = (const float*)d_in[2];   // [8192]
    const float* amp   = (const float*)d_in[3];   // [8192]
    const float* bias  = (const float*)d_in[4];   // [8192]
    float* out = (float*)d_out;

    const size_t xt_bytes = (size_t)IN_F * BATCH * sizeof(float);
    const int use_xt = (ws_size >= xt_bytes) ? 1 : 0;
    float* xT = (float*)d_ws;

    if (use_xt) {
        transpose_x_kern<<<IN_F / 64, 256, 0, stream>>>(x, xT);
    }
    dim3 grid(OUT_F / TQ, BATCH / ROWS);
    gauss_fc_kern<<<grid, 256, 0, stream>>>(x, xT,
                                            (const float4*)mu, (const float4*)sigma,
                                            amp, bias, out, use_xt);
}